// Round 4
// baseline (82.203 us; speedup 1.0000x reference)
//
#include <hip/hip_runtime.h>
#include <hip/hip_bf16.h>

#define NROW 4096      // 2B
#define HALFB 2048     // B
#define CDIM 1024
#define INV_T 2.0f     // 1/0.5
#define NBLK16 16      // NROW / 256
#define NTRI16 136     // NBLK16*(NBLK16+1)/2
#define NT 16          // CDIM / 64 K-tiles

typedef __attribute__((ext_vector_type(8))) short bf16x8;
typedef __attribute__((ext_vector_type(4))) float f32x4;

__device__ __forceinline__ float bf2f(unsigned short u) {
    union { unsigned int u; float f; } c; c.u = ((unsigned int)u) << 16; return c.f;
}
__device__ __forceinline__ unsigned short f2bf(float f) {
    __hip_bfloat16 h = __float2bfloat16(f);
    union { __hip_bfloat16 h; unsigned short u; } c; c.h = h; return c.u;
}

// ---------------- Kernel 1: row L2-normalize + bf16 pack (+ zero den) ----------------
__global__ __launch_bounds__(256) void normalize_kernel(
        const float* __restrict__ z1, const float* __restrict__ z2,
        unsigned short* __restrict__ zb, float* __restrict__ den) {
    const int row = blockIdx.x;
    const int t = threadIdx.x;
    if (row < 16) den[row * 256 + t] = 0.f;   // NROW = 16*256; gemm is stream-ordered after
    const float* src = (row < HALFB) ? (z1 + (size_t)row * CDIM)
                                     : (z2 + (size_t)(row - HALFB) * CDIM);
    float4 v = ((const float4*)src)[t];
    float ss = v.x * v.x + v.y * v.y + v.z * v.z + v.w * v.w;
    #pragma unroll
    for (int off = 1; off < 64; off <<= 1) ss += __shfl_xor(ss, off);
    __shared__ float wsum[4];
    const int lane = t & 63, wv = t >> 6;
    if (lane == 0) wsum[wv] = ss;
    __syncthreads();
    const float tot = wsum[0] + wsum[1] + wsum[2] + wsum[3];
    const float scale = 1.0f / fmaxf(sqrtf(tot), 1e-12f);
    ushort4 p;
    p.x = f2bf(v.x * scale);
    p.y = f2bf(v.y * scale);
    p.z = f2bf(v.z * scale);
    p.w = f2bf(v.w * scale);
    ((ushort4*)(zb + (size_t)row * CDIM))[t] = p;
}

// ---------------- Kernel 2: 256^2-tile triangle GEMM, counted-vmcnt phases ----------------
// grid = 136 blocks x 512 threads (8 waves, 2Mx4N). Tile 256x256, BK=64 as 2x32 K-halves.
// Per phase: {12 ds_read_b128 ; stage 1 K-half of next K-tile (4 gload_lds) ;
//             barrier ; setprio(1) 32 MFMA setprio(0) ; vmcnt(4) ; barrier}
// vmcnt(4) = current phase's own 4 stage loads stay in flight; needed data (issued
// 2 phases earlier) is guaranteed complete. Per-wave vmcnt -> barrier -> cross-wave safe.
// LDS 128KB: [2 dbuf][2 khalf][256 rows x 32 cols] bf16 for A and B.
// Swizzle: 16B slot ^= (row>>1)&3, applied on global SOURCE and ds_read (linear LDS dest).
__global__ __launch_bounds__(512, 2) void gemm_den_kernel(
        const unsigned short* __restrict__ zb, float* __restrict__ den,
        float* __restrict__ pos) {
    __shared__ __align__(16) unsigned short As[2][2][256 * 32];
    __shared__ __align__(16) unsigned short Bs[2][2][256 * 32];

    // XCD swizzle (136 = 8*17, bijective), then triangle decode
    const int orig = blockIdx.x;
    int swz = (orig & 7) * (NTRI16 / 8) + (orig >> 3);
    int bi = 0, rem = swz;
    while (rem >= NBLK16 - bi) { rem -= NBLK16 - bi; ++bi; }
    const int bj = bi + rem;
    const int i0 = bi * 256, j0 = bj * 256;
    const bool diag = (bi == bj);
    const bool is_pos = (bj == bi + NBLK16 / 2);   // tile diagonal holds S[i, i+B]

    const int tid = threadIdx.x;
    const int wave = tid >> 6, lane = tid & 63;
    const int wr = wave >> 2, wc = wave & 3;       // 2 x 4 wave grid; per-wave 128x64

    f32x4 acc[8][4];
    #pragma unroll
    for (int im = 0; im < 8; im++)
        #pragma unroll
        for (int jc = 0; jc < 4; jc++) acc[im][jc] = (f32x4){0.f, 0.f, 0.f, 0.f};

    // staging lane geometry: 16 rows x 32 cols per wave-instruction (1KB)
    const int srow = lane >> 2;                          // 0..15
    const int sslot = (lane & 3) ^ ((lane >> 3) & 3);    // pre-swizzled 16B slot

    // stage one K-half (A + B) of K-tile kt into buf: 4 gload_lds per wave
    auto stage = [&](int buf, int kt, int kh) {
        const int k0 = kt * 64 + kh * 32 + sslot * 8;
        #pragma unroll
        for (int q = 0; q < 2; ++q) {
            const int r = q * 128 + wave * 16;           // wave-uniform row base
            const unsigned short* ga = zb + (size_t)(i0 + r + srow) * CDIM + k0;
            __builtin_amdgcn_global_load_lds(
                (const __attribute__((address_space(1))) void*)ga,
                (__attribute__((address_space(3))) void*)&As[buf][kh][r * 32],
                16, 0, 0);
            const unsigned short* gb = zb + (size_t)(j0 + r + srow) * CDIM + k0;
            __builtin_amdgcn_global_load_lds(
                (const __attribute__((address_space(1))) void*)gb,
                (__attribute__((address_space(3))) void*)&Bs[buf][kh][r * 32],
                16, 0, 0);
        }
    };

    // prologue: both K-halves of K-tile 0; leave khi's 4 loads in flight
    stage(0, 0, 0);
    stage(0, 0, 1);
    asm volatile("s_waitcnt vmcnt(4)" ::: "memory");
    __builtin_amdgcn_s_barrier();
    __builtin_amdgcn_sched_barrier(0);

    const int l15 = lane & 15, ks = lane >> 4;

    for (int t = 0; t < NT; ++t) {
        const int buf = t & 1;
        const bool stg = (t + 1 < NT);
        #pragma unroll
        for (int kh = 0; kh < 2; ++kh) {
            // ds-load fragments for this K-half
            bf16x8 a[8], b[4];
            #pragma unroll
            for (int im = 0; im < 8; ++im) {
                const int row = wr * 128 + im * 16 + l15;
                const int slot = ks ^ ((row >> 1) & 3);
                a[im] = *(const bf16x8*)(&As[buf][kh][row * 32 + slot * 8]);
            }
            #pragma unroll
            for (int jc = 0; jc < 4; ++jc) {
                const int row = wc * 64 + jc * 16 + l15;
                const int slot = ks ^ ((row >> 1) & 3);
                b[jc] = *(const bf16x8*)(&Bs[buf][kh][row * 32 + slot * 8]);
            }
            // stage same K-half of next K-tile into the other buffer
            if (stg) stage(buf ^ 1, t + 1, kh);
            __builtin_amdgcn_s_barrier();
            __builtin_amdgcn_sched_barrier(0);
            __builtin_amdgcn_s_setprio(1);
            #pragma unroll
            for (int im = 0; im < 8; ++im)
                #pragma unroll
                for (int jc = 0; jc < 4; ++jc)
                    acc[im][jc] = __builtin_amdgcn_mfma_f32_16x16x32_bf16(
                        a[im], b[jc], acc[im][jc], 0, 0, 0);
            __builtin_amdgcn_s_setprio(0);
            // counted wait: keep this phase's 4 stage loads in flight; the data the
            // NEXT phase reads (staged one phase before this one) is now complete.
            if (stg) asm volatile("s_waitcnt vmcnt(4)" ::: "memory");
            else     asm volatile("s_waitcnt vmcnt(0)" ::: "memory");
            __builtin_amdgcn_s_barrier();
            __builtin_amdgcn_sched_barrier(0);
        }
    }

    // ---- positives: tiles with j0 == i0 + 2048 hold S[i, i+B] on their diagonal
    if (is_pos && (wc >> 1) == wr) {
        #pragma unroll
        for (int jc = 0; jc < 4; ++jc) {
            if (ks == (l15 >> 2)) {
                pos[i0 + wr * 128 + (wc & 1) * 64 + jc * 16 + l15] =
                    acc[(wc & 1) * 4 + jc][jc][l15 & 3];
            }
        }
    }

    // ---- epilogue: e = exp(2*s); row-sums -> den[i-panel]; col-sums -> den[j-panel]
    float cs[4] = {0.f, 0.f, 0.f, 0.f};
    #pragma unroll
    for (int im = 0; im < 8; ++im) {
        #pragma unroll
        for (int r = 0; r < 4; ++r) {
            float rs = 0.f;
            #pragma unroll
            for (int jc = 0; jc < 4; ++jc) {
                const float e = __expf(INV_T * acc[im][jc][r]);
                rs += e;
                cs[jc] += e;
            }
            rs += __shfl_xor(rs, 1);
            rs += __shfl_xor(rs, 2);
            rs += __shfl_xor(rs, 4);
            rs += __shfl_xor(rs, 8);
            if (l15 == 0) {
                const int grow = i0 + wr * 128 + im * 16 + ks * 4 + r;
                atomicAdd(&den[grow], rs);
            }
        }
    }
    if (!diag) {
        #pragma unroll
        for (int jc = 0; jc < 4; ++jc) {
            float c = cs[jc];
            c += __shfl_xor(c, 16);
            c += __shfl_xor(c, 32);
            if (lane < 16) {
                const int gcol = j0 + wc * 64 + jc * 16 + lane;
                atomicAdd(&den[gcol], c);
            }
        }
    }
}

// ---------------- Kernel 3: final loss ----------------
__global__ __launch_bounds__(256) void loss_kernel(
        const float* __restrict__ den, const float* __restrict__ pos,
        float* __restrict__ out) {
    const float E2 = 7.3890560989306495f;  // exp(2) = diagonal term
    const int tid = threadIdx.x;
    float acc = 0.f;
    for (int i = tid; i < NROW; i += 256)
        acc += INV_T * pos[i & (HALFB - 1)] - logf(den[i] - E2);
    #pragma unroll
    for (int off = 1; off < 64; off <<= 1) acc += __shfl_xor(acc, off);
    __shared__ float wsum[4];
    const int lane = tid & 63, wv = tid >> 6;
    if (lane == 0) wsum[wv] = acc;
    __syncthreads();
    if (tid == 0) out[0] = -(wsum[0] + wsum[1] + wsum[2] + wsum[3]) * (1.0f / NROW);
}

extern "C" void kernel_launch(void* const* d_in, const int* in_sizes, int n_in,
                              void* d_out, int out_size, void* d_ws, size_t ws_size,
                              hipStream_t stream) {
    const float* z1 = (const float*)d_in[0];
    const float* z2 = (const float*)d_in[1];
    float* out = (float*)d_out;

    unsigned short* zb = (unsigned short*)d_ws;                      // 8 MB
    float* den = (float*)((char*)d_ws + (size_t)NROW * CDIM * 2);    // 16 KB
    float* pos = den + NROW;                                         // 8 KB

    normalize_kernel<<<NROW, 256, 0, stream>>>(z1, z2, zb, den);
    gemm_den_kernel<<<NTRI16, 512, 0, stream>>>(zb, den, pos);
    loss_kernel<<<1, 256, 0, stream>>>(den, pos, out);
}

// Round 5
// 54.812 us; speedup vs baseline: 1.4997x; 1.4997x over previous
//
#include <hip/hip_runtime.h>
#include <hip/hip_bf16.h>

#define NROW 4096      // 2B
#define HALFB 2048     // B
#define CDIM 1024
#define INV_T 2.0f     // 1/0.5
#define NBLK16 16      // NROW / 256
#define NTRI16 136     // NBLK16*(NBLK16+1)/2
#define NT 16          // CDIM / 64 K-tiles

typedef __attribute__((ext_vector_type(8))) short bf16x8;
typedef __attribute__((ext_vector_type(4))) float f32x4;

__device__ __forceinline__ float bf2f(unsigned short u) {
    union { unsigned int u; float f; } c; c.u = ((unsigned int)u) << 16; return c.f;
}
__device__ __forceinline__ unsigned short f2bf(float f) {
    __hip_bfloat16 h = __float2bfloat16(f);
    union { __hip_bfloat16 h; unsigned short u; } c; c.h = h; return c.u;
}

// ---------------- Kernel 1: row L2-normalize + bf16 pack (+ zero den) ----------------
__global__ __launch_bounds__(256) void normalize_kernel(
        const float* __restrict__ z1, const float* __restrict__ z2,
        unsigned short* __restrict__ zb, float* __restrict__ den) {
    const int row = blockIdx.x;
    const int t = threadIdx.x;
    if (row < 16) den[row * 256 + t] = 0.f;   // NROW = 16*256; gemm is stream-ordered after
    const float* src = (row < HALFB) ? (z1 + (size_t)row * CDIM)
                                     : (z2 + (size_t)(row - HALFB) * CDIM);
    float4 v = ((const float4*)src)[t];
    float ss = v.x * v.x + v.y * v.y + v.z * v.z + v.w * v.w;
    #pragma unroll
    for (int off = 1; off < 64; off <<= 1) ss += __shfl_xor(ss, off);
    __shared__ float wsum[4];
    const int lane = t & 63, wv = t >> 6;
    if (lane == 0) wsum[wv] = ss;
    __syncthreads();
    const float tot = wsum[0] + wsum[1] + wsum[2] + wsum[3];
    const float scale = 1.0f / fmaxf(sqrtf(tot), 1e-12f);
    ushort4 p;
    p.x = f2bf(v.x * scale);
    p.y = f2bf(v.y * scale);
    p.z = f2bf(v.z * scale);
    p.w = f2bf(v.w * scale);
    ((ushort4*)(zb + (size_t)row * CDIM))[t] = p;
}

// ---------------- Kernel 2: 256^2-tile triangle GEMM, counted-vmcnt phases ----------------
// grid = 136 blocks x 512 threads (8 waves, 2Mx4N). Tile 256x256, BK=64 as 2x32 K-halves.
// Per phase: {12 ds_read_b128 ; stage 1 K-half of next K-tile (4 gload_lds) ;
//             barrier ; setprio(1) 32 MFMA setprio(0) ; vmcnt(4) ; barrier}
// Invariant: at each phase start, outstanding vmem <= 4 = NEXT phase's stage loads;
// the data this phase reads was drained by the previous phase's vmcnt(4).
// LDS 128KB: [2 dbuf][2 khalf][256 rows x 32 cols] bf16 for A and B.
// Swizzle: 16B slot ^= (row>>1)&3, on global SOURCE and ds_read (linear LDS dest).
// NOTE (rule #20): ALL acc[][] accesses must be compile-time-indexed or the
// accumulator spills to scratch (R4: 132MB scratch writes, 3x regression).
__global__ __launch_bounds__(512, 2) void gemm_den_kernel(
        const unsigned short* __restrict__ zb, float* __restrict__ den,
        float* __restrict__ pos) {
    __shared__ __align__(16) unsigned short As[2][2][256 * 32];
    __shared__ __align__(16) unsigned short Bs[2][2][256 * 32];

    // XCD swizzle (136 = 8*17, bijective), then triangle decode
    const int orig = blockIdx.x;
    int swz = (orig & 7) * (NTRI16 / 8) + (orig >> 3);
    int bi = 0, rem = swz;
    while (rem >= NBLK16 - bi) { rem -= NBLK16 - bi; ++bi; }
    const int bj = bi + rem;
    const int i0 = bi * 256, j0 = bj * 256;
    const bool diag = (bi == bj);
    const bool is_pos = (bj == bi + NBLK16 / 2);   // tile diagonal holds S[i, i+B]

    const int tid = threadIdx.x;
    const int wave = tid >> 6, lane = tid & 63;
    const int wr = wave >> 2, wc = wave & 3;       // 2 x 4 wave grid; per-wave 128x64

    f32x4 acc[8][4];
    #pragma unroll
    for (int im = 0; im < 8; im++)
        #pragma unroll
        for (int jc = 0; jc < 4; jc++) acc[im][jc] = (f32x4){0.f, 0.f, 0.f, 0.f};

    // staging lane geometry: 16 rows x 32 cols per wave-instruction (1KB)
    const int srow = lane >> 2;                          // 0..15
    const int sslot = (lane & 3) ^ ((lane >> 3) & 3);    // pre-swizzled 16B slot

    // stage one K-half (A + B) of K-tile kt into buf: 4 gload_lds per wave
    auto stage = [&](int buf, int kt, int kh) {
        const int k0 = kt * 64 + kh * 32 + sslot * 8;
        #pragma unroll
        for (int q = 0; q < 2; ++q) {
            const int r = q * 128 + wave * 16;           // wave-uniform row base
            const unsigned short* ga = zb + (size_t)(i0 + r + srow) * CDIM + k0;
            __builtin_amdgcn_global_load_lds(
                (const __attribute__((address_space(1))) void*)ga,
                (__attribute__((address_space(3))) void*)&As[buf][kh][r * 32],
                16, 0, 0);
            const unsigned short* gb = zb + (size_t)(j0 + r + srow) * CDIM + k0;
            __builtin_amdgcn_global_load_lds(
                (const __attribute__((address_space(1))) void*)gb,
                (__attribute__((address_space(3))) void*)&Bs[buf][kh][r * 32],
                16, 0, 0);
        }
    };

    // prologue: both K-halves of K-tile 0; leave kh1's 4 loads in flight
    stage(0, 0, 0);
    stage(0, 0, 1);
    asm volatile("s_waitcnt vmcnt(4)" ::: "memory");
    __builtin_amdgcn_s_barrier();
    __builtin_amdgcn_sched_barrier(0);

    const int l15 = lane & 15, ks = lane >> 4;

    for (int t = 0; t < NT; ++t) {
        const int buf = t & 1;
        const bool stg = (t + 1 < NT);
        #pragma unroll
        for (int kh = 0; kh < 2; ++kh) {
            // ds-load fragments for this K-half
            bf16x8 a[8], b[4];
            #pragma unroll
            for (int im = 0; im < 8; ++im) {
                const int row = wr * 128 + im * 16 + l15;
                const int slot = ks ^ ((row >> 1) & 3);
                a[im] = *(const bf16x8*)(&As[buf][kh][row * 32 + slot * 8]);
            }
            #pragma unroll
            for (int jc = 0; jc < 4; ++jc) {
                const int row = wc * 64 + jc * 16 + l15;
                const int slot = ks ^ ((row >> 1) & 3);
                b[jc] = *(const bf16x8*)(&Bs[buf][kh][row * 32 + slot * 8]);
            }
            // stage same K-half of next K-tile into the other buffer
            if (stg) stage(buf ^ 1, t + 1, kh);
            __builtin_amdgcn_s_barrier();
            __builtin_amdgcn_sched_barrier(0);
            __builtin_amdgcn_s_setprio(1);
            #pragma unroll
            for (int im = 0; im < 8; ++im)
                #pragma unroll
                for (int jc = 0; jc < 4; ++jc)
                    acc[im][jc] = __builtin_amdgcn_mfma_f32_16x16x32_bf16(
                        a[im], b[jc], acc[im][jc], 0, 0, 0);
            __builtin_amdgcn_s_setprio(0);
            if (stg) asm volatile("s_waitcnt vmcnt(4)" ::: "memory");
            else     asm volatile("s_waitcnt vmcnt(0)" ::: "memory");
            __builtin_amdgcn_s_barrier();
            __builtin_amdgcn_sched_barrier(0);
        }
    }

    // ---- positives: tiles with j0 == i0 + 2048 hold S[i, i+B] on their diagonal.
    // Diagonal element: row_frag == col_frag -> im == c1*4+jc and l15 == ks*4+r.
    // All acc indices are compile-time (c1 selected via branch-free ternary of two
    // constant-indexed reads) to keep acc in registers.
    if (is_pos && (wc >> 1) == wr) {
        const int c1 = wc & 1;
        #pragma unroll
        for (int jc = 0; jc < 4; ++jc) {
            #pragma unroll
            for (int r = 0; r < 4; ++r) {
                const float v = c1 ? acc[4 + jc][jc][r] : acc[jc][jc][r];
                if (l15 == ks * 4 + r)
                    pos[i0 + wr * 128 + c1 * 64 + jc * 16 + l15] = v;
            }
        }
    }

    // ---- epilogue: e = exp(2*s); row-sums -> den[i-panel]; col-sums -> den[j-panel]
    float cs[4] = {0.f, 0.f, 0.f, 0.f};
    #pragma unroll
    for (int im = 0; im < 8; ++im) {
        #pragma unroll
        for (int r = 0; r < 4; ++r) {
            float rs = 0.f;
            #pragma unroll
            for (int jc = 0; jc < 4; ++jc) {
                const float e = __expf(INV_T * acc[im][jc][r]);
                rs += e;
                cs[jc] += e;
            }
            rs += __shfl_xor(rs, 1);
            rs += __shfl_xor(rs, 2);
            rs += __shfl_xor(rs, 4);
            rs += __shfl_xor(rs, 8);
            if (l15 == 0) {
                const int grow = i0 + wr * 128 + im * 16 + ks * 4 + r;
                atomicAdd(&den[grow], rs);
            }
        }
    }
    if (!diag) {
        #pragma unroll
        for (int jc = 0; jc < 4; ++jc) {
            float c = cs[jc];
            c += __shfl_xor(c, 16);
            c += __shfl_xor(c, 32);
            if (lane < 16) {
                const int gcol = j0 + wc * 64 + jc * 16 + lane;
                atomicAdd(&den[gcol], c);
            }
        }
    }
}

// ---------------- Kernel 3: final loss ----------------
__global__ __launch_bounds__(256) void loss_kernel(
        const float* __restrict__ den, const float* __restrict__ pos,
        float* __restrict__ out) {
    const float E2 = 7.3890560989306495f;  // exp(2) = diagonal term
    const int tid = threadIdx.x;
    float acc = 0.f;
    for (int i = tid; i < NROW; i += 256)
        acc += INV_T * pos[i & (HALFB - 1)] - logf(den[i] - E2);
    #pragma unroll
    for (int off = 1; off < 64; off <<= 1) acc += __shfl_xor(acc, off);
    __shared__ float wsum[4];
    const int lane = tid & 63, wv = tid >> 6;
    if (lane == 0) wsum[wv] = acc;
    __syncthreads();
    if (tid == 0) out[0] = -(wsum[0] + wsum[1] + wsum[2] + wsum[3]) * (1.0f / NROW);
}

extern "C" void kernel_launch(void* const* d_in, const int* in_sizes, int n_in,
                              void* d_out, int out_size, void* d_ws, size_t ws_size,
                              hipStream_t stream) {
    const float* z1 = (const float*)d_in[0];
    const float* z2 = (const float*)d_in[1];
    float* out = (float*)d_out;

    unsigned short* zb = (unsigned short*)d_ws;                      // 8 MB
    float* den = (float*)((char*)d_ws + (size_t)NROW * CDIM * 2);    // 16 KB
    float* pos = den + NROW;                                         // 8 KB

    normalize_kernel<<<NROW, 256, 0, stream>>>(z1, z2, zb, den);
    gemm_den_kernel<<<NTRI16, 512, 0, stream>>>(zb, den, pos);
    loss_kernel<<<1, 256, 0, stream>>>(den, pos, out);
}